// Round 1
// baseline (285.777 us; speedup 1.0000x reference)
//
#include <hip/hip_runtime.h>
#include <hip/hip_bf16.h>

// Problem constants (fixed shapes: N=M=8192, D=1024)
#define D_K 1024
#define TILE 128
#define BK 32

typedef __bf16 bf16x8 __attribute__((ext_vector_type(8)));
typedef float floatx4 __attribute__((ext_vector_type(4)));

__device__ __forceinline__ unsigned short f2bf(float x) {
    __hip_bfloat16 h = __float2bfloat16(x);
    return *reinterpret_cast<unsigned short*>(&h);
}

// async global->LDS, 16B per lane. LDS dest is wave-uniform base + lane*16;
// we pass per-lane ptrs that already satisfy base+lane*16 so it's consistent.
__device__ __forceinline__ void gl_lds16(const __hip_bfloat16* g, __hip_bfloat16* l) {
    __builtin_amdgcn_global_load_lds(
        (const __attribute__((address_space(1))) unsigned int*)g,
        (__attribute__((address_space(3))) unsigned int*)l,
        16, 0, 0);
}

// ---------------------------------------------------------------------------
// Kernel 1: per-row normalize q,n -> bf16; compute positive-pair term per row.
// One block (256 threads) per row; each thread owns 4 consecutive floats.
// ---------------------------------------------------------------------------
__global__ __launch_bounds__(256)
void prep_kernel(const float* __restrict__ q, const float* __restrict__ p,
                 const float* __restrict__ ng,
                 __hip_bfloat16* __restrict__ qn, __hip_bfloat16* __restrict__ nn,
                 float* __restrict__ posp) {
    const int row = blockIdx.x;
    const int t = threadIdx.x;
    const size_t base = (size_t)row * D_K;

    float4 qa = ((const float4*)(q + base))[t];
    float4 pa = ((const float4*)(p + base))[t];
    float4 na = ((const float4*)(ng + base))[t];

    float4 v;
    v.x = qa.x*qa.x + qa.y*qa.y + qa.z*qa.z + qa.w*qa.w;   // |q|^2
    v.y = pa.x*pa.x + pa.y*pa.y + pa.z*pa.z + pa.w*pa.w;   // |p|^2
    v.z = qa.x*pa.x + qa.y*pa.y + qa.z*pa.z + qa.w*pa.w;   // q.p
    v.w = na.x*na.x + na.y*na.y + na.z*na.z + na.w*na.w;   // |n|^2

    for (int off = 32; off > 0; off >>= 1) {
        v.x += __shfl_down(v.x, off);
        v.y += __shfl_down(v.y, off);
        v.z += __shfl_down(v.z, off);
        v.w += __shfl_down(v.w, off);
    }
    __shared__ float4 red[4];
    const int wid = t >> 6, lane = t & 63;
    if (lane == 0) red[wid] = v;
    __syncthreads();
    float4 tot;
    tot.x = red[0].x + red[1].x + red[2].x + red[3].x;
    tot.y = red[0].y + red[1].y + red[2].y + red[3].y;
    tot.z = red[0].z + red[1].z + red[2].z + red[3].z;
    tot.w = red[0].w + red[1].w + red[2].w + red[3].w;

    const float rq = 1.0f / fmaxf(sqrtf(tot.x), 1e-8f);
    const float rn = 1.0f / fmaxf(sqrtf(tot.w), 1e-8f);

    ushort4 pk;
    pk.x = f2bf(qa.x * rq); pk.y = f2bf(qa.y * rq);
    pk.z = f2bf(qa.z * rq); pk.w = f2bf(qa.w * rq);
    *(ushort4*)(qn + base + 4 * (size_t)t) = pk;
    pk.x = f2bf(na.x * rn); pk.y = f2bf(na.y * rn);
    pk.z = f2bf(na.z * rn); pk.w = f2bf(na.w * rn);
    *(ushort4*)(nn + base + 4 * (size_t)t) = pk;

    if (t == 0) {
        const float rp = 1.0f / fmaxf(sqrtf(tot.y), 1e-8f);
        const float sim = tot.z * rq * rp;
        const float ap = fmaxf(1.5f - sim, 0.0f);          // clamp_min(-s + (1+m), 0), m=0.5
        const float sp = -ap * (sim - 0.5f);               // -ap*(s - (1-m))
        posp[row] = __expf(sp - 4.0f);                     // shift C=4 (s_pos <= 3.75)
    }
}

// ---------------------------------------------------------------------------
// Kernel 2: fused bf16 MFMA GEMM (Q̂ · N̂ᵀ) + circle transform + partial expsum.
// 128x128 tile / block, 4 waves, BK=32 (one 16x16x32 mfma per frag pair),
// global_load_lds width=16 staging (m97 structure). Global sum is layout-
// independent, so no C/D index mapping is needed in the epilogue.
// ---------------------------------------------------------------------------
__global__ __launch_bounds__(256, 2)
void gemm_lse_kernel(const __hip_bfloat16* __restrict__ A,
                     const __hip_bfloat16* __restrict__ B,
                     float* __restrict__ negp) {
    __shared__ __hip_bfloat16 As[TILE * BK];
    __shared__ __hip_bfloat16 Bs[TILE * BK];

    const int tid = threadIdx.x;
    const int wid = tid >> 6;
    const int lane = tid & 63;
    const int tile_m = blockIdx.y * TILE;
    const int tile_n = blockIdx.x * TILE;

    const int wave_m = (wid & 1) * 64;
    const int wave_n = (wid >> 1) * 64;
    const int quad = lane >> 4;
    const int r = lane & 15;

    floatx4 acc[4][4] = {};

    // staging: 512 16B-chunks per tile (128 rows x 4 chunks), 2 per lane
    const int c0 = wid * 128 + lane;
    const int c1 = c0 + 64;
    const int r0 = c0 >> 2, kc0 = (c0 & 3) * 8;
    const int r1 = c1 >> 2, kc1 = (c1 & 3) * 8;

    const __hip_bfloat16* Abase = A + (size_t)tile_m * D_K;
    const __hip_bfloat16* Bbase = B + (size_t)tile_n * D_K;

    for (int k0 = 0; k0 < D_K; k0 += BK) {
        gl_lds16(Abase + (size_t)r0 * D_K + k0 + kc0, &As[c0 * 8]);
        gl_lds16(Abase + (size_t)r1 * D_K + k0 + kc1, &As[c1 * 8]);
        gl_lds16(Bbase + (size_t)r0 * D_K + k0 + kc0, &Bs[c0 * 8]);
        gl_lds16(Bbase + (size_t)r1 * D_K + k0 + kc1, &Bs[c1 * 8]);
        __syncthreads();   // drains vmcnt for the DMA + barrier

        bf16x8 a[4], b[4];
#pragma unroll
        for (int i = 0; i < 4; i++)
            a[i] = *(const bf16x8*)&As[(wave_m + i * 16 + r) * BK + quad * 8];
#pragma unroll
        for (int j = 0; j < 4; j++)
            b[j] = *(const bf16x8*)&Bs[(wave_n + j * 16 + r) * BK + quad * 8];

#pragma unroll
        for (int i = 0; i < 4; i++)
#pragma unroll
            for (int j = 0; j < 4; j++)
                acc[i][j] = __builtin_amdgcn_mfma_f32_16x16x32_bf16(a[i], b[j], acc[i][j], 0, 0, 0);

        __syncthreads();   // protect LDS before next stage
    }

    // epilogue: circle-loss transform + exp-sum (shift C=4; s_neg <= 3.75)
    float lsum = 0.0f;
#pragma unroll
    for (int i = 0; i < 4; i++)
#pragma unroll
        for (int j = 0; j < 4; j++)
#pragma unroll
            for (int e = 0; e < 4; e++) {
                const float s = acc[i][j][e];
                const float an = fmaxf(s + 1.5f, 0.0f);    // clamp_min(s + (1+m), 0)
                const float sn = an * (s + 0.5f);          // an*(s - delta_n), delta_n = -(1-m)
                lsum += __expf(sn - 4.0f);
            }
    for (int off = 32; off > 0; off >>= 1) lsum += __shfl_down(lsum, off);
    __shared__ float red[4];
    if (lane == 0) red[wid] = lsum;
    __syncthreads();
    if (tid == 0)
        negp[blockIdx.y * gridDim.x + blockIdx.x] = red[0] + red[1] + red[2] + red[3];
}

// ---------------------------------------------------------------------------
// Kernel 3: reduce partials, assemble softplus(lse_neg + lse_pos).
// ---------------------------------------------------------------------------
__global__ __launch_bounds__(256)
void finalize_kernel(const float* __restrict__ negp, int n_neg,
                     const float* __restrict__ posp, int n_pos,
                     float* __restrict__ out) {
    double sn = 0.0, sp = 0.0;
    for (int i = threadIdx.x; i < n_neg; i += 256) sn += (double)negp[i];
    for (int i = threadIdx.x; i < n_pos; i += 256) sp += (double)posp[i];
    for (int off = 32; off > 0; off >>= 1) {
        sn += __shfl_down(sn, off);
        sp += __shfl_down(sp, off);
    }
    __shared__ double rn[4], rp[4];
    const int wid = threadIdx.x >> 6, lane = threadIdx.x & 63;
    if (lane == 0) { rn[wid] = sn; rp[wid] = sp; }
    __syncthreads();
    if (threadIdx.x == 0) {
        const double NS = rn[0] + rn[1] + rn[2] + rn[3];
        const double PS = rp[0] + rp[1] + rp[2] + rp[3];
        const double x = (4.0 + log(NS)) + (4.0 + log(PS));
        const double spl = (x > 30.0) ? x : log1p(exp(x));
        out[0] = (float)spl;
    }
}

extern "C" void kernel_launch(void* const* d_in, const int* in_sizes, int n_in,
                              void* d_out, int out_size, void* d_ws, size_t ws_size,
                              hipStream_t stream) {
    const float* q = (const float*)d_in[0];
    const float* p = (const float*)d_in[1];
    const float* ng = (const float*)d_in[2];
    // d_in[3] (text_neg_index) is unused in this branch of the reference.

    const int N = in_sizes[3];          // 8192
    const int D = in_sizes[0] / N;      // 1024 (== D_K)
    const int M = in_sizes[2] / D;      // 8192 (== N here)

    char* ws = (char*)d_ws;
    __hip_bfloat16* qn = (__hip_bfloat16*)ws;
    __hip_bfloat16* nn = (__hip_bfloat16*)(ws + (size_t)N * D * 2);
    float* negp = (float*)(ws + (size_t)(N + M) * D * 2);
    const int n_neg = (N / TILE) * (M / TILE);
    float* posp = negp + n_neg;

    // N == M for this problem, so one prep pass covers q/p rows and n rows.
    prep_kernel<<<N, 256, 0, stream>>>(q, p, ng, qn, nn, posp);
    gemm_lse_kernel<<<dim3(M / TILE, N / TILE), 256, 0, stream>>>(qn, nn, negp);
    finalize_kernel<<<1, 256, 0, stream>>>(negp, n_neg, posp, N, (float*)d_out);
}

// Round 2
// 199.754 us; speedup vs baseline: 1.4306x; 1.4306x over previous
//
#include <hip/hip_runtime.h>
#include <hip/hip_bf16.h>
#include <hip/hip_fp8.h>

// Problem constants (fixed shapes: N=M=8192, D=1024)
#define D_K 1024
#define TILE 128
#define BKB 128   // K-bytes (= K elements, fp8) staged per iteration

typedef int intx8 __attribute__((ext_vector_type(8)));
typedef float floatx4 __attribute__((ext_vector_type(4)));

__device__ __forceinline__ unsigned char f2fp8(float x) {
    __hip_fp8_e4m3 v(x);   // OCP e4m3fn (gfx950 HW format)
    return v.__x;
}

// async global->LDS, 16B per lane. LDS dest is wave-uniform base + lane*16.
__device__ __forceinline__ void gl_lds16(const void* g, void* l) {
    __builtin_amdgcn_global_load_lds(
        (const __attribute__((address_space(1))) unsigned int*)g,
        (__attribute__((address_space(3))) unsigned int*)l,
        16, 0, 0);
}

// Load one 32B A/B fragment (K-block `quad`) from a row whose 16B chunks are
// stored XOR-swizzled: LDS slot s holds global chunk s ^ e (e = row & 7).
__device__ __forceinline__ intx8 ld_frag(const unsigned char* rowbase, int quad, int e) {
    const int4 lo = *(const int4*)(rowbase + (((2 * quad) ^ e) * 16));
    const int4 hi = *(const int4*)(rowbase + (((2 * quad + 1) ^ e) * 16));
    intx8 v;
    v[0] = lo.x; v[1] = lo.y; v[2] = lo.z; v[3] = lo.w;
    v[4] = hi.x; v[5] = hi.y; v[6] = hi.z; v[7] = hi.w;
    return v;
}

// ---------------------------------------------------------------------------
// Kernel 1: per-row normalize q,n -> fp8 e4m3; positive-pair term per row.
// One block (256 threads) per row; each thread owns 4 consecutive floats.
// ---------------------------------------------------------------------------
__global__ __launch_bounds__(256)
void prep_kernel(const float* __restrict__ q, const float* __restrict__ p,
                 const float* __restrict__ ng,
                 unsigned char* __restrict__ qn, unsigned char* __restrict__ nn,
                 float* __restrict__ posp) {
    const int row = blockIdx.x;
    const int t = threadIdx.x;
    const size_t base = (size_t)row * D_K;

    float4 qa = ((const float4*)(q + base))[t];
    float4 pa = ((const float4*)(p + base))[t];
    float4 na = ((const float4*)(ng + base))[t];

    float4 v;
    v.x = qa.x*qa.x + qa.y*qa.y + qa.z*qa.z + qa.w*qa.w;   // |q|^2
    v.y = pa.x*pa.x + pa.y*pa.y + pa.z*pa.z + pa.w*pa.w;   // |p|^2
    v.z = qa.x*pa.x + qa.y*pa.y + qa.z*pa.z + qa.w*pa.w;   // q.p
    v.w = na.x*na.x + na.y*na.y + na.z*na.z + na.w*na.w;   // |n|^2

    for (int off = 32; off > 0; off >>= 1) {
        v.x += __shfl_down(v.x, off);
        v.y += __shfl_down(v.y, off);
        v.z += __shfl_down(v.z, off);
        v.w += __shfl_down(v.w, off);
    }
    __shared__ float4 red[4];
    const int wid = t >> 6, lane = t & 63;
    if (lane == 0) red[wid] = v;
    __syncthreads();
    float4 tot;
    tot.x = red[0].x + red[1].x + red[2].x + red[3].x;
    tot.y = red[0].y + red[1].y + red[2].y + red[3].y;
    tot.z = red[0].z + red[1].z + red[2].z + red[3].z;
    tot.w = red[0].w + red[1].w + red[2].w + red[3].w;

    const float rq = 1.0f / fmaxf(sqrtf(tot.x), 1e-8f);
    const float rn = 1.0f / fmaxf(sqrtf(tot.w), 1e-8f);

    uchar4 pk;
    pk.x = f2fp8(qa.x * rq); pk.y = f2fp8(qa.y * rq);
    pk.z = f2fp8(qa.z * rq); pk.w = f2fp8(qa.w * rq);
    *(uchar4*)(qn + base + 4 * (size_t)t) = pk;
    pk.x = f2fp8(na.x * rn); pk.y = f2fp8(na.y * rn);
    pk.z = f2fp8(na.z * rn); pk.w = f2fp8(na.w * rn);
    *(uchar4*)(nn + base + 4 * (size_t)t) = pk;

    if (t == 0) {
        const float rp = 1.0f / fmaxf(sqrtf(tot.y), 1e-8f);
        const float sim = tot.z * rq * rp;
        const float ap = fmaxf(1.5f - sim, 0.0f);          // clamp_min(-s + (1+m), 0), m=0.5
        const float sp = -ap * (sim - 0.5f);               // -ap*(s - (1-m))
        posp[row] = __expf(sp - 4.0f);                     // shift C=4 (s_pos <= 3.75)
    }
}

// ---------------------------------------------------------------------------
// Kernel 2: fused MX-fp8 MFMA GEMM (Q̂ · N̂ᵀ) + circle transform + partial
// expsum. 128x128 tile, 4 waves, BK=128 fp8 (one 16x16x128 mfma_scale per
// frag pair, scales = 1.0). global_load_lds width=16 staging with global-side
// 16B XOR swizzle so frag ds_read_b128s are bank-conflict-free.
// ---------------------------------------------------------------------------
__global__ __launch_bounds__(256, 2)
void gemm_lse_fp8(const unsigned char* __restrict__ A,
                  const unsigned char* __restrict__ B,
                  float* __restrict__ negp) {
    __shared__ unsigned char As[TILE * BKB];   // 16 KB
    __shared__ unsigned char Bs[TILE * BKB];   // 16 KB

    const int tid = threadIdx.x;
    const int wid = tid >> 6;
    const int lane = tid & 63;
    const int tile_m = blockIdx.y * TILE;
    const int tile_n = blockIdx.x * TILE;

    const int wave_m = (wid & 1) * 64;
    const int wave_n = (wid >> 1) * 64;
    const int quad = lane >> 4;
    const int r = lane & 15;
    const int e = r & 7;

    floatx4 acc[4][4] = {};

    // staging: 1024 16B-chunks per matrix per stage, 4 per thread each.
    // LDS is linear (slot = cc); global source chunk is XOR-swizzled.
    int lds_off[4];
    size_t src_off[4];
#pragma unroll
    for (int s = 0; s < 4; s++) {
        const int cc = s * 256 + tid;
        const int row = cc >> 3, slot = cc & 7;
        lds_off[s] = cc * 16;
        src_off[s] = (size_t)row * D_K + (size_t)((slot ^ (row & 7)) * 16);
    }
    const unsigned char* Ab = A + (size_t)tile_m * D_K;
    const unsigned char* Bb = B + (size_t)tile_n * D_K;

    for (int k0 = 0; k0 < D_K; k0 += BKB) {
#pragma unroll
        for (int s = 0; s < 4; s++) {
            gl_lds16(Ab + src_off[s] + k0, &As[lds_off[s]]);
            gl_lds16(Bb + src_off[s] + k0, &Bs[lds_off[s]]);
        }
        __syncthreads();   // drains vmcnt for the DMA + barrier

        intx8 a[4], b[4];
#pragma unroll
        for (int i = 0; i < 4; i++)
            a[i] = ld_frag(&As[(wave_m + i * 16 + r) * BKB], quad, e);
#pragma unroll
        for (int j = 0; j < 4; j++)
            b[j] = ld_frag(&Bs[(wave_n + j * 16 + r) * BKB], quad, e);

#pragma unroll
        for (int i = 0; i < 4; i++)
#pragma unroll
            for (int j = 0; j < 4; j++)
                acc[i][j] = __builtin_amdgcn_mfma_scale_f32_16x16x128_f8f6f4(
                    a[i], b[j], acc[i][j],
                    0, 0,                 // cbsz=0: A fp8 e4m3; blgp=0: B fp8 e4m3
                    0, 0x7f7f7f7f,        // scale_a opsel, scale_a bytes = 127 -> 1.0
                    0, 0x7f7f7f7f);       // scale_b opsel, scale_b bytes = 127 -> 1.0

        __syncthreads();   // protect LDS before next stage
    }

    // epilogue: circle-loss transform + exp-sum (shift C=4; s_neg <= 3.95)
    float lsum = 0.0f;
#pragma unroll
    for (int i = 0; i < 4; i++)
#pragma unroll
        for (int j = 0; j < 4; j++)
#pragma unroll
            for (int el = 0; el < 4; el++) {
                const float s = acc[i][j][el];
                const float an = fmaxf(s + 1.5f, 0.0f);    // clamp_min(s + (1+m), 0)
                const float sn = an * (s + 0.5f);          // an*(s - delta_n), delta_n = -(1-m)
                lsum += __expf(sn - 4.0f);
            }
    for (int off = 32; off > 0; off >>= 1) lsum += __shfl_down(lsum, off);
    __shared__ float red[4];
    if (lane == 0) red[wid] = lsum;
    __syncthreads();
    if (tid == 0)
        negp[blockIdx.y * gridDim.x + blockIdx.x] = red[0] + red[1] + red[2] + red[3];
}

// ---------------------------------------------------------------------------
// Kernel 3: reduce partials, assemble softplus(lse_neg + lse_pos).
// ---------------------------------------------------------------------------
__global__ __launch_bounds__(256)
void finalize_kernel(const float* __restrict__ negp, int n_neg,
                     const float* __restrict__ posp, int n_pos,
                     float* __restrict__ out) {
    double sn = 0.0, sp = 0.0;
    for (int i = threadIdx.x; i < n_neg; i += 256) sn += (double)negp[i];
    for (int i = threadIdx.x; i < n_pos; i += 256) sp += (double)posp[i];
    for (int off = 32; off > 0; off >>= 1) {
        sn += __shfl_down(sn, off);
        sp += __shfl_down(sp, off);
    }
    __shared__ double rn[4], rp[4];
    const int wid = threadIdx.x >> 6, lane = threadIdx.x & 63;
    if (lane == 0) { rn[wid] = sn; rp[wid] = sp; }
    __syncthreads();
    if (threadIdx.x == 0) {
        const double NS = rn[0] + rn[1] + rn[2] + rn[3];
        const double PS = rp[0] + rp[1] + rp[2] + rp[3];
        const double x = (4.0 + log(NS)) + (4.0 + log(PS));
        const double spl = (x > 30.0) ? x : log1p(exp(x));
        out[0] = (float)spl;
    }
}

extern "C" void kernel_launch(void* const* d_in, const int* in_sizes, int n_in,
                              void* d_out, int out_size, void* d_ws, size_t ws_size,
                              hipStream_t stream) {
    const float* q = (const float*)d_in[0];
    const float* p = (const float*)d_in[1];
    const float* ng = (const float*)d_in[2];
    // d_in[3] (text_neg_index) is unused in this branch of the reference.

    const int N = in_sizes[3];          // 8192
    const int D = in_sizes[0] / N;      // 1024 (== D_K)
    const int M = in_sizes[2] / D;      // 8192

    char* ws = (char*)d_ws;
    unsigned char* qn = (unsigned char*)ws;
    unsigned char* nn = (unsigned char*)(ws + (size_t)N * D);
    float* negp = (float*)(ws + (size_t)(N + M) * D);
    const int n_neg = (N / TILE) * (M / TILE);
    float* posp = negp + n_neg;

    // N == M for this problem, so one prep pass covers q/p rows and n rows.
    prep_kernel<<<N, 256, 0, stream>>>(q, p, ng, qn, nn, posp);
    gemm_lse_fp8<<<dim3(M / TILE, N / TILE), 256, 0, stream>>>(qn, nn, negp);
    finalize_kernel<<<1, 256, 0, stream>>>(negp, n_neg, posp, N, (float*)d_out);
}